// Round 1
// baseline (467.155 us; speedup 1.0000x reference)
//
#include <hip/hip_runtime.h>
#include <hip/hip_bf16.h>

#define NUM_EXPERTS 16
#define TOPK 2
#define IN_DIM 1024
#define OUT_DIM 1024
#define BTOK 8192

typedef __attribute__((ext_vector_type(4))) float f32x4;
typedef __attribute__((ext_vector_type(4))) int   i32x4;
typedef __attribute__((ext_vector_type(8))) short short8;
typedef __attribute__((ext_vector_type(8))) __bf16 bf16x8;

// ---- helpers -------------------------------------------------------------

static __device__ inline unsigned short f2bf(float f) {
    union { float f; unsigned u; } v; v.f = f;
    unsigned u = v.u;
    unsigned r = (u + 0x7FFFu + ((u >> 16) & 1u)) >> 16;  // RNE
    return (unsigned short)r;
}

static __device__ inline short8 pack8(float4 a, float4 b) {
    short8 s;
    s[0] = (short)f2bf(a.x); s[1] = (short)f2bf(a.y);
    s[2] = (short)f2bf(a.z); s[3] = (short)f2bf(a.w);
    s[4] = (short)f2bf(b.x); s[5] = (short)f2bf(b.y);
    s[6] = (short)f2bf(b.z); s[7] = (short)f2bf(b.w);
    return s;
}

static __device__ inline bf16x8 ldfrag(const short* p) {
    i32x4 v = *(const i32x4*)p;                 // ds_read_b128
    return __builtin_bit_cast(bf16x8, v);
}

// ---- kernel 1: gating ----------------------------------------------------
// grid: 256 blocks x 256 threads; each block = 4 waves x 8 tokens = 32 tokens
__global__ __launch_bounds__(256) void gate_kernel(
    const float* __restrict__ x, const float* __restrict__ Wg,
    const float* __restrict__ bg,
    int* __restrict__ eidx, float* __restrict__ prob,
    int* __restrict__ counts, float* __restrict__ partialLoad)
{
    __shared__ float sWg[NUM_EXPERTS * IN_DIM];   // 64 KB
    __shared__ float sBg[NUM_EXPERTS];
    __shared__ float sLoad[NUM_EXPERTS];

    int tid = threadIdx.x;
    for (int i = tid; i < NUM_EXPERTS * IN_DIM / 4; i += 256)
        ((float4*)sWg)[i] = ((const float4*)Wg)[i];
    if (tid < NUM_EXPERTS) { sBg[tid] = bg[tid]; sLoad[tid] = 0.f; }
    __syncthreads();

    int lane = tid & 63;
    int wave = tid >> 6;

    for (int i = 0; i < 8; ++i) {
        int t = blockIdx.x * 32 + wave * 8 + i;
        const float4* xr = (const float4*)(x + (size_t)t * IN_DIM);

        float acc[NUM_EXPERTS];
        #pragma unroll
        for (int e = 0; e < NUM_EXPERTS; ++e) acc[e] = 0.f;

        #pragma unroll
        for (int pass = 0; pass < 4; ++pass) {
            float4 xv = xr[pass * 64 + lane];
            int kb = pass * 256 + lane * 4;
            #pragma unroll
            for (int e = 0; e < NUM_EXPERTS; ++e) {
                float4 wv = *(const float4*)&sWg[e * IN_DIM + kb];
                acc[e] += xv.x * wv.x + xv.y * wv.y + xv.z * wv.z + xv.w * wv.w;
            }
        }
        // 64-lane reduce per expert
        #pragma unroll
        for (int e = 0; e < NUM_EXPERTS; ++e) {
            float v = acc[e];
            #pragma unroll
            for (int off = 32; off; off >>= 1) v += __shfl_xor(v, off);
            acc[e] = v;
        }
        if (lane == 0) {
            float v0 = -1e30f, v1 = -1e30f; int i0 = 0, i1 = 0;
            #pragma unroll
            for (int e = 0; e < NUM_EXPERTS; ++e) {
                float v = acc[e] + sBg[e];
                if (v > v0) { v1 = v0; i1 = i0; v0 = v; i0 = e; }
                else if (v > v1) { v1 = v; i1 = e; }
            }
            float t1 = expf(v1 - v0);           // v1 <= v0
            float inv = 1.f / (1.f + t1);
            float p0 = inv, p1 = t1 * inv;
            eidx[2 * t]     = i0;  eidx[2 * t + 1] = i1;
            prob[2 * t]     = p0;  prob[2 * t + 1] = p1;
            atomicAdd(&counts[i0], 1);
            atomicAdd(&counts[i1], 1);
            atomicAdd(&sLoad[i0], p0);
            atomicAdd(&sLoad[i1], p1);
        }
    }
    __syncthreads();
    if (tid < NUM_EXPERTS) partialLoad[blockIdx.x * NUM_EXPERTS + tid] = sLoad[tid];
}

// ---- kernel 2: offsets + aux loss -----------------------------------------
__global__ __launch_bounds__(64) void finalize_gate(
    const int* __restrict__ counts, int* __restrict__ offsets,
    int* __restrict__ cursor, const float* __restrict__ partialLoad,
    int nPart, float* __restrict__ aux_out)
{
    __shared__ float load[NUM_EXPERTS];
    int tid = threadIdx.x;
    if (tid < NUM_EXPERTS) {
        float s = 0.f;
        for (int b = 0; b < nPart; ++b) s += partialLoad[b * NUM_EXPERTS + tid];
        load[tid] = s;
    }
    __syncthreads();
    if (tid == 0) {
        int off = 0;
        for (int e = 0; e < NUM_EXPERTS; ++e) {
            offsets[e] = off; cursor[e] = off; off += counts[e];
        }
        offsets[NUM_EXPERTS] = off;
        float mean = 0.f;
        for (int e = 0; e < NUM_EXPERTS; ++e) mean += load[e];
        mean *= (1.f / NUM_EXPERTS);
        float var = 0.f;
        for (int e = 0; e < NUM_EXPERTS; ++e) {
            float d = load[e] - mean; var += d * d;
        }
        var *= (1.f / (NUM_EXPERTS - 1));       // ddof=1
        aux_out[0] = sqrtf(var) / mean;
    }
}

// ---- kernel 3: counting-sort scatter --------------------------------------
// grid: 32 blocks x 256 threads, token per thread
__global__ __launch_bounds__(256) void scatter_kernel(
    const int* __restrict__ eidx, int* __restrict__ cursor,
    int* __restrict__ perm)
{
    __shared__ int lc[NUM_EXPERTS];
    __shared__ int lbase[NUM_EXPERTS];
    int tid = threadIdx.x;
    if (tid < NUM_EXPERTS) lc[tid] = 0;
    __syncthreads();
    int t = blockIdx.x * 256 + tid;
    int e0 = eidx[2 * t], e1 = eidx[2 * t + 1];
    int lp0 = atomicAdd(&lc[e0], 1);
    int lp1 = atomicAdd(&lc[e1], 1);
    __syncthreads();
    if (tid < NUM_EXPERTS) lbase[tid] = atomicAdd(&cursor[tid], lc[tid]);
    __syncthreads();
    perm[lbase[e0] + lp0] = 2 * t;
    perm[lbase[e1] + lp1] = 2 * t + 1;
}

// ---- kernel 4: grouped expert GEMM -----------------------------------------
// C[g, o] = sum_k x[token(g), k] * We[e, o, k];  out[token] += p * (C + be[e,o])
// tile 128(M) x 128(N) x 64(K), 4 waves, each wave 64x64 via 4x4 MFMA 16x16x32
#define BM 128
#define BN 128
#define BK 64

__global__ __launch_bounds__(256) void expert_gemm(
    const float* __restrict__ x, const float* __restrict__ We,
    const float* __restrict__ be,
    const int* __restrict__ perm, const float* __restrict__ prob,
    const int* __restrict__ offsets, float* __restrict__ out)
{
    int e  = blockIdx.z;
    int g0 = offsets[e], g1 = offsets[e + 1];
    int ne = g1 - g0;
    int tm = blockIdx.y;
    if (tm * BM >= ne) return;
    int tn = blockIdx.x;

    __shared__ short As[BM * BK];   // 16 KB, XOR-swizzled 16B chunks
    __shared__ short Bs[BN * BK];   // 16 KB

    int tid  = threadIdx.x;
    int lane = tid & 63;
    int wave = tid >> 6;
    int wm = wave >> 1, wn = wave & 1;

    // staging assignment: chunk c = tid + 256*i ; row = c/8 ; s = c%8 (16B chunks)
    const float* aSrc[4]; bool aValid[4];
    #pragma unroll
    for (int i = 0; i < 4; ++i) {
        int c = tid + 256 * i;
        int row = c >> 3;
        int gIdx = g0 + tm * BM + row;
        if (gIdx < g1) {
            int tok = perm[gIdx] >> 1;
            aSrc[i] = x + (size_t)tok * IN_DIM;
            aValid[i] = true;
        } else { aSrc[i] = x; aValid[i] = false; }
    }
    const float* bSrcBase = We + (size_t)e * OUT_DIM * IN_DIM;

    f32x4 acc[4][4];
    #pragma unroll
    for (int m = 0; m < 4; ++m)
        #pragma unroll
        for (int n = 0; n < 4; ++n) {
            acc[m][n][0] = 0.f; acc[m][n][1] = 0.f;
            acc[m][n][2] = 0.f; acc[m][n][3] = 0.f;
        }

    for (int k0 = 0; k0 < IN_DIM; k0 += BK) {
        __syncthreads();
        // stage A (gathered token rows), f32 -> bf16
        #pragma unroll
        for (int i = 0; i < 4; ++i) {
            int c = tid + 256 * i;
            int row = c >> 3, s = c & 7;
            float4 v0, v1;
            if (aValid[i]) {
                const float* p = aSrc[i] + k0 + s * 8;
                v0 = *(const float4*)p;
                v1 = *(const float4*)(p + 4);
            } else {
                v0 = make_float4(0.f, 0.f, 0.f, 0.f); v1 = v0;
            }
            int ss = s ^ (row & 7);
            *(short8*)&As[row * BK + ss * 8] = pack8(v0, v1);
        }
        // stage B (We rows), f32 -> bf16
        #pragma unroll
        for (int i = 0; i < 4; ++i) {
            int c = tid + 256 * i;
            int row = c >> 3, s = c & 7;
            int o = tn * BN + row;
            const float* p = bSrcBase + (size_t)o * IN_DIM + k0 + s * 8;
            float4 v0 = *(const float4*)p;
            float4 v1 = *(const float4*)(p + 4);
            int ss = s ^ (row & 7);
            *(short8*)&Bs[row * BK + ss * 8] = pack8(v0, v1);
        }
        __syncthreads();

        #pragma unroll
        for (int ks = 0; ks < 2; ++ks) {
            bf16x8 aF[4], bF[4];
            #pragma unroll
            for (int m = 0; m < 4; ++m) {
                int row = wm * 64 + m * 16 + (lane & 15);
                int chunk = (ks * 4 + (lane >> 4)) ^ (row & 7);
                aF[m] = ldfrag(&As[row * BK + chunk * 8]);
            }
            #pragma unroll
            for (int n = 0; n < 4; ++n) {
                int row = wn * 64 + n * 16 + (lane & 15);
                int chunk = (ks * 4 + (lane >> 4)) ^ (row & 7);
                bF[n] = ldfrag(&Bs[row * BK + chunk * 8]);
            }
            #pragma unroll
            for (int m = 0; m < 4; ++m)
                #pragma unroll
                for (int n = 0; n < 4; ++n)
                    acc[m][n] = __builtin_amdgcn_mfma_f32_16x16x32_bf16(
                        aF[m], bF[n], acc[m][n], 0, 0, 0);
        }
    }

    // epilogue: out[token, col] += p * (acc + be[e, col])
    int   rowTok[4][4];
    float rowP[4][4];
    bool  rowV[4][4];
    #pragma unroll
    for (int m = 0; m < 4; ++m)
        #pragma unroll
        for (int r = 0; r < 4; ++r) {
            int row = wm * 64 + m * 16 + (lane >> 4) * 4 + r;
            int gIdx = g0 + tm * BM + row;
            if (gIdx < g1) {
                int entry = perm[gIdx];
                rowTok[m][r] = entry >> 1;
                rowP[m][r]   = prob[entry];
                rowV[m][r]   = true;
            } else rowV[m][r] = false;
        }
    #pragma unroll
    for (int n = 0; n < 4; ++n) {
        int col = tn * BN + wn * 64 + n * 16 + (lane & 15);
        float bias = be[e * OUT_DIM + col];
        #pragma unroll
        for (int m = 0; m < 4; ++m)
            #pragma unroll
            for (int r = 0; r < 4; ++r)
                if (rowV[m][r]) {
                    float v = acc[m][n][r] + bias;
                    atomicAdd(&out[(size_t)rowTok[m][r] * OUT_DIM + col],
                              rowP[m][r] * v);
                }
    }
}

// ---- launch ----------------------------------------------------------------
extern "C" void kernel_launch(void* const* d_in, const int* in_sizes, int n_in,
                              void* d_out, int out_size, void* d_ws, size_t ws_size,
                              hipStream_t stream) {
    const float* x  = (const float*)d_in[0];
    const float* Wg = (const float*)d_in[1];
    const float* bg = (const float*)d_in[2];
    const float* We = (const float*)d_in[3];
    const float* be = (const float*)d_in[4];
    float* out = (float*)d_out;

    // workspace layout
    char* w = (char*)d_ws;
    int*   counts      = (int*)w;    w += 64;
    int*   offsets     = (int*)w;    w += 128;
    int*   cursor      = (int*)w;    w += 64;
    int*   eidx        = (int*)w;    w += (size_t)2 * BTOK * 4;
    float* probArr     = (float*)w;  w += (size_t)2 * BTOK * 4;
    int*   perm        = (int*)w;    w += (size_t)2 * BTOK * 4 + 512;
    float* partialLoad = (float*)w;  w += 256 * NUM_EXPERTS * 4;

    // zero output (epilogue accumulates atomically) and counts
    hipMemsetAsync(d_out, 0, (size_t)out_size * sizeof(float), stream);
    hipMemsetAsync(counts, 0, 64, stream);

    gate_kernel<<<BTOK / 32, 256, 0, stream>>>(x, Wg, bg, eidx, probArr,
                                               counts, partialLoad);
    finalize_gate<<<1, 64, 0, stream>>>(counts, offsets, cursor, partialLoad,
                                        BTOK / 32, out + (size_t)BTOK * OUT_DIM);
    scatter_kernel<<<BTOK / 256, 256, 0, stream>>>(eidx, cursor, perm);

    dim3 grid(OUT_DIM / BN, (TOPK * BTOK) / BM, NUM_EXPERTS);
    expert_gemm<<<grid, 256, 0, stream>>>(x, We, be, perm, probArr, offsets, out);
}

// Round 2
// 228.595 us; speedup vs baseline: 2.0436x; 2.0436x over previous
//
#include <hip/hip_runtime.h>
#include <hip/hip_bf16.h>

#define NUM_EXPERTS 16
#define IN_DIM 1024
#define OUT_DIM 1024
#define BTOK 8192
#define NSLOT (2 * BTOK)

typedef __attribute__((ext_vector_type(4))) float f32x4;
typedef __attribute__((ext_vector_type(4))) int   i32x4;
typedef __attribute__((ext_vector_type(4))) unsigned short u16x4;
typedef __attribute__((ext_vector_type(8))) short short8;
typedef __attribute__((ext_vector_type(8))) __bf16 bf16x8;

// ---- helpers -------------------------------------------------------------

static __device__ inline unsigned short f2bf(float f) {
    union { float f; unsigned u; } v; v.f = f;
    unsigned u = v.u;
    unsigned r = (u + 0x7FFFu + ((u >> 16) & 1u)) >> 16;  // RNE
    return (unsigned short)r;
}

static __device__ inline short8 pack8(float4 a, float4 b) {
    short8 s;
    s[0] = (short)f2bf(a.x); s[1] = (short)f2bf(a.y);
    s[2] = (short)f2bf(a.z); s[3] = (short)f2bf(a.w);
    s[4] = (short)f2bf(b.x); s[5] = (short)f2bf(b.y);
    s[6] = (short)f2bf(b.z); s[7] = (short)f2bf(b.w);
    return s;
}

static __device__ inline bf16x8 ldfrag(const unsigned short* p) {
    i32x4 v = *(const i32x4*)p;                 // ds_read_b128
    return __builtin_bit_cast(bf16x8, v);
}

#define GLOAD_LDS16(g, l)                                                     \
    __builtin_amdgcn_global_load_lds(                                         \
        (const __attribute__((address_space(1))) void*)(g),                   \
        (__attribute__((address_space(3))) void*)(l), 16, 0, 0)

// ---- kernel 0: We f32 -> bf16 ---------------------------------------------
__global__ __launch_bounds__(256) void convert_we(
    const float* __restrict__ We, unsigned short* __restrict__ Web)
{
    size_t i = ((size_t)blockIdx.x * 256 + threadIdx.x) * 8;
    const float4* s = (const float4*)(We + i);
    float4 v0 = s[0], v1 = s[1];
    *(short8*)(Web + i) = pack8(v0, v1);
}

// ---- kernel 1: gating (+ x -> bf16 copy) -----------------------------------
// grid: 256 blocks x 256 threads; each block = 4 waves x 8 tokens = 32 tokens
__global__ __launch_bounds__(256) void gate_kernel(
    const float* __restrict__ x, const float* __restrict__ Wg,
    const float* __restrict__ bg,
    int* __restrict__ eidx, float* __restrict__ prob,
    float* __restrict__ partialLoad, int* __restrict__ partialCount,
    unsigned short* __restrict__ xb)
{
    __shared__ float sWg[NUM_EXPERTS * IN_DIM];   // 64 KB
    __shared__ float sBg[NUM_EXPERTS];
    __shared__ float sLoad[NUM_EXPERTS];
    __shared__ int   sCnt[NUM_EXPERTS];

    int tid = threadIdx.x;
    for (int i = tid; i < NUM_EXPERTS * IN_DIM / 4; i += 256)
        ((float4*)sWg)[i] = ((const float4*)Wg)[i];
    if (tid < NUM_EXPERTS) { sBg[tid] = bg[tid]; sLoad[tid] = 0.f; sCnt[tid] = 0; }
    __syncthreads();

    int lane = tid & 63;
    int wave = tid >> 6;
    const bool wb = (xb != nullptr);

    for (int i = 0; i < 8; ++i) {
        int t = blockIdx.x * 32 + wave * 8 + i;
        const float4* xr = (const float4*)(x + (size_t)t * IN_DIM);

        float acc[NUM_EXPERTS];
        #pragma unroll
        for (int e = 0; e < NUM_EXPERTS; ++e) acc[e] = 0.f;

        #pragma unroll
        for (int pass = 0; pass < 4; ++pass) {
            float4 xv = xr[pass * 64 + lane];
            if (wb) {
                u16x4 b;
                b[0] = f2bf(xv.x); b[1] = f2bf(xv.y);
                b[2] = f2bf(xv.z); b[3] = f2bf(xv.w);
                *(u16x4*)(xb + (size_t)t * IN_DIM + (pass * 64 + lane) * 4) = b;
            }
            int kb = pass * 256 + lane * 4;
            #pragma unroll
            for (int e = 0; e < NUM_EXPERTS; ++e) {
                float4 wv = *(const float4*)&sWg[e * IN_DIM + kb];
                acc[e] += xv.x * wv.x + xv.y * wv.y + xv.z * wv.z + xv.w * wv.w;
            }
        }
        // 64-lane reduce per expert
        #pragma unroll
        for (int e = 0; e < NUM_EXPERTS; ++e) {
            float v = acc[e];
            #pragma unroll
            for (int off = 32; off; off >>= 1) v += __shfl_xor(v, off);
            acc[e] = v;
        }
        if (lane == 0) {
            float v0 = -1e30f, v1 = -1e30f; int i0 = 0, i1 = 0;
            #pragma unroll
            for (int e = 0; e < NUM_EXPERTS; ++e) {
                float v = acc[e] + sBg[e];
                if (v > v0) { v1 = v0; i1 = i0; v0 = v; i0 = e; }
                else if (v > v1) { v1 = v; i1 = e; }
            }
            float t1 = expf(v1 - v0);           // v1 <= v0
            float inv = 1.f / (1.f + t1);
            float p0 = inv, p1 = t1 * inv;
            eidx[2 * t]     = i0;  eidx[2 * t + 1] = i1;
            prob[2 * t]     = p0;  prob[2 * t + 1] = p1;
            atomicAdd(&sCnt[i0], 1);
            atomicAdd(&sCnt[i1], 1);
            atomicAdd(&sLoad[i0], p0);
            atomicAdd(&sLoad[i1], p1);
        }
    }
    __syncthreads();
    if (tid < NUM_EXPERTS) {
        partialLoad[blockIdx.x * NUM_EXPERTS + tid]  = sLoad[tid];
        partialCount[blockIdx.x * NUM_EXPERTS + tid] = sCnt[tid];
    }
}

// ---- kernel 2: offsets + aux loss -----------------------------------------
__global__ __launch_bounds__(64) void finalize_gate(
    int* __restrict__ offsets, int* __restrict__ cursor,
    const float* __restrict__ partialLoad, const int* __restrict__ partialCount,
    int nPart, float* __restrict__ aux_out)
{
    __shared__ float load[NUM_EXPERTS];
    __shared__ int   cnt[NUM_EXPERTS];
    int tid = threadIdx.x;
    if (tid < NUM_EXPERTS) {
        float s = 0.f; int c = 0;
        #pragma unroll 8
        for (int b = 0; b < nPart; ++b) {
            s += partialLoad[b * NUM_EXPERTS + tid];
            c += partialCount[b * NUM_EXPERTS + tid];
        }
        load[tid] = s; cnt[tid] = c;
    }
    __syncthreads();
    if (tid == 0) {
        int off = 0;
        for (int e = 0; e < NUM_EXPERTS; ++e) {
            offsets[e] = off; cursor[e] = off; off += cnt[e];
        }
        offsets[NUM_EXPERTS] = off;
        float mean = 0.f;
        for (int e = 0; e < NUM_EXPERTS; ++e) mean += load[e];
        mean *= (1.f / NUM_EXPERTS);
        float var = 0.f;
        for (int e = 0; e < NUM_EXPERTS; ++e) {
            float d = load[e] - mean; var += d * d;
        }
        var *= (1.f / (NUM_EXPERTS - 1));       // ddof=1
        aux_out[0] = sqrtf(var) / mean;
    }
}

// ---- kernel 3: counting-sort scatter --------------------------------------
__global__ __launch_bounds__(256) void scatter_kernel(
    const int* __restrict__ eidx, int* __restrict__ cursor,
    int* __restrict__ perm)
{
    __shared__ int lc[NUM_EXPERTS];
    __shared__ int lbase[NUM_EXPERTS];
    int tid = threadIdx.x;
    if (tid < NUM_EXPERTS) lc[tid] = 0;
    __syncthreads();
    int t = blockIdx.x * 256 + tid;
    int e0 = eidx[2 * t], e1 = eidx[2 * t + 1];
    int lp0 = atomicAdd(&lc[e0], 1);
    int lp1 = atomicAdd(&lc[e1], 1);
    __syncthreads();
    if (tid < NUM_EXPERTS) lbase[tid] = atomicAdd(&cursor[tid], lc[tid]);
    __syncthreads();
    perm[lbase[e0] + lp0] = 2 * t;
    perm[lbase[e1] + lp1] = 2 * t + 1;
}

// ---- kernel 4 (full): bf16 grouped GEMM with global_load_lds ---------------
// tile 128(M) x 128(N) x 64(K), 4 waves; LDS XOR-swizzle via pre-swizzled src
__global__ __launch_bounds__(256) void expert_gemm_bf16(
    const unsigned short* __restrict__ xb, const unsigned short* __restrict__ Web,
    const float* __restrict__ be,
    const int* __restrict__ perm, const float* __restrict__ prob,
    const int* __restrict__ offsets, float* __restrict__ out)
{
    // XCD-aware decomposition: XCD k owns experts {2k, 2k+1} (L2 locality).
    int lin = blockIdx.x;
    int xcd = lin & 7, j = lin >> 3;
    int e = xcd * 2 + (j & 1);
    int j2 = j >> 1;                 // [0,1024)
    int tm = j2 >> 3, tn = j2 & 7;

    int g0 = offsets[e], g1 = offsets[e + 1];
    int ne = g1 - g0;
    if (tm * 128 >= ne) return;

    __shared__ unsigned short As[128 * 64];   // 16 KB
    __shared__ unsigned short Bs[128 * 64];   // 16 KB

    int tid = threadIdx.x, lane = tid & 63, w = tid >> 6;
    int wm = w >> 1, wn = w & 1;

    // staging: chunk c = 256*i + 64*w + lane; LDS slot (row=c>>3, ss=c&7);
    // source chunk s = ss ^ (row&7)  -> reads use chunk ^ (row&7) (conflict-free)
    const char* aPtr[4];
    const char* bPtr[4];
    #pragma unroll
    for (int i = 0; i < 4; ++i) {
        int c = 256 * i + 64 * w + lane;
        int row = c >> 3, ss = c & 7;
        int s = ss ^ (row & 7);
        int gIdx = g0 + tm * 128 + row;
        if (gIdx > NSLOT - 1) gIdx = NSLOT - 1;         // clamp; masked at store
        int tok = perm[gIdx] >> 1;
        aPtr[i] = (const char*)(xb + (size_t)tok * IN_DIM + s * 8);
        bPtr[i] = (const char*)(Web + ((size_t)e * OUT_DIM + tn * 128 + row) * IN_DIM + s * 8);
    }

    f32x4 acc[4][4];
    #pragma unroll
    for (int m = 0; m < 4; ++m)
        #pragma unroll
        for (int n = 0; n < 4; ++n) {
            acc[m][n][0] = 0.f; acc[m][n][1] = 0.f;
            acc[m][n][2] = 0.f; acc[m][n][3] = 0.f;
        }

    for (int k0 = 0; k0 < IN_DIM; k0 += 64) {
        #pragma unroll
        for (int i = 0; i < 4; ++i)
            GLOAD_LDS16(aPtr[i] + k0 * 2, &As[(256 * i + 64 * w) * 8]);
        #pragma unroll
        for (int i = 0; i < 4; ++i)
            GLOAD_LDS16(bPtr[i] + k0 * 2, &Bs[(256 * i + 64 * w) * 8]);
        __syncthreads();   // compiler drains vmcnt before s_barrier

        #pragma unroll
        for (int ks = 0; ks < 2; ++ks) {
            bf16x8 aF[4], bF[4];
            #pragma unroll
            for (int m = 0; m < 4; ++m) {
                int row = wm * 64 + m * 16 + (lane & 15);
                int chunk = (ks * 4 + (lane >> 4)) ^ (row & 7);
                aF[m] = ldfrag(&As[row * 64 + chunk * 8]);
            }
            #pragma unroll
            for (int n = 0; n < 4; ++n) {
                int row = wn * 64 + n * 16 + (lane & 15);
                int chunk = (ks * 4 + (lane >> 4)) ^ (row & 7);
                bF[n] = ldfrag(&Bs[row * 64 + chunk * 8]);
            }
            #pragma unroll
            for (int m = 0; m < 4; ++m)
                #pragma unroll
                for (int n = 0; n < 4; ++n)
                    acc[m][n] = __builtin_amdgcn_mfma_f32_16x16x32_bf16(
                        aF[m], bF[n], acc[m][n], 0, 0, 0);
        }
        __syncthreads();   // all ds_reads done before next-tile overwrite
    }

    // epilogue: out[token, col] += p * (acc + be[e, col])
    int   rowTok[4][4];
    float rowP[4][4];
    bool  rowV[4][4];
    #pragma unroll
    for (int m = 0; m < 4; ++m)
        #pragma unroll
        for (int r = 0; r < 4; ++r) {
            int row = wm * 64 + m * 16 + (lane >> 4) * 4 + r;
            int gIdx = g0 + tm * 128 + row;
            if (gIdx < g1) {
                int entry = perm[gIdx];
                rowTok[m][r] = entry >> 1;
                rowP[m][r]   = prob[entry];
                rowV[m][r]   = true;
            } else rowV[m][r] = false;
        }
    #pragma unroll
    for (int n = 0; n < 4; ++n) {
        int col = tn * 128 + wn * 64 + n * 16 + (lane & 15);
        float bias = be[e * OUT_DIM + col];
        #pragma unroll
        for (int m = 0; m < 4; ++m)
            #pragma unroll
            for (int r = 0; r < 4; ++r)
                if (rowV[m][r]) {
                    float v = acc[m][n][r] + bias;
                    atomicAdd(&out[(size_t)rowTok[m][r] * OUT_DIM + col],
                              rowP[m][r] * v);
                }
    }
}

// ---- kernel 4 (fallback): f32-input grouped GEMM (round-1 proven) ----------
__global__ __launch_bounds__(256) void expert_gemm_f32(
    const float* __restrict__ x, const float* __restrict__ We,
    const float* __restrict__ be,
    const int* __restrict__ perm, const float* __restrict__ prob,
    const int* __restrict__ offsets, float* __restrict__ out)
{
    int e  = blockIdx.z;
    int g0 = offsets[e], g1 = offsets[e + 1];
    int ne = g1 - g0;
    int tm = blockIdx.y;
    if (tm * 128 >= ne) return;
    int tn = blockIdx.x;

    __shared__ unsigned short As[128 * 64];
    __shared__ unsigned short Bs[128 * 64];

    int tid  = threadIdx.x;
    int lane = tid & 63;
    int wave = tid >> 6;
    int wm = wave >> 1, wn = wave & 1;

    const float* aSrc[4]; bool aValid[4];
    #pragma unroll
    for (int i = 0; i < 4; ++i) {
        int c = tid + 256 * i;
        int row = c >> 3;
        int gIdx = g0 + tm * 128 + row;
        if (gIdx < g1) {
            int tok = perm[gIdx] >> 1;
            aSrc[i] = x + (size_t)tok * IN_DIM;
            aValid[i] = true;
        } else { aSrc[i] = x; aValid[i] = false; }
    }
    const float* bSrcBase = We + (size_t)e * OUT_DIM * IN_DIM;

    f32x4 acc[4][4];
    #pragma unroll
    for (int m = 0; m < 4; ++m)
        #pragma unroll
        for (int n = 0; n < 4; ++n) {
            acc[m][n][0] = 0.f; acc[m][n][1] = 0.f;
            acc[m][n][2] = 0.f; acc[m][n][3] = 0.f;
        }

    for (int k0 = 0; k0 < IN_DIM; k0 += 64) {
        __syncthreads();
        #pragma unroll
        for (int i = 0; i < 4; ++i) {
            int c = tid + 256 * i;
            int row = c >> 3, s = c & 7;
            float4 v0, v1;
            if (aValid[i]) {
                const float* p = aSrc[i] + k0 + s * 8;
                v0 = *(const float4*)p;
                v1 = *(const float4*)(p + 4);
            } else {
                v0 = make_float4(0.f, 0.f, 0.f, 0.f); v1 = v0;
            }
            int ss = s ^ (row & 7);
            *(short8*)&As[row * 64 + ss * 8] = pack8(v0, v1);
        }
        #pragma unroll
        for (int i = 0; i < 4; ++i) {
            int c = tid + 256 * i;
            int row = c >> 3, s = c & 7;
            int o = tn * 128 + row;
            const float* p = bSrcBase + (size_t)o * IN_DIM + k0 + s * 8;
            float4 v0 = *(const float4*)p;
            float4 v1 = *(const float4*)(p + 4);
            int ss = s ^ (row & 7);
            *(short8*)&Bs[row * 64 + ss * 8] = pack8(v0, v1);
        }
        __syncthreads();

        #pragma unroll
        for (int ks = 0; ks < 2; ++ks) {
            bf16x8 aF[4], bF[4];
            #pragma unroll
            for (int m = 0; m < 4; ++m) {
                int row = wm * 64 + m * 16 + (lane & 15);
                int chunk = (ks * 4 + (lane >> 4)) ^ (row & 7);
                aF[m] = ldfrag(&As[row * 64 + chunk * 8]);
            }
            #pragma unroll
            for (int n = 0; n < 4; ++n) {
                int row = wn * 64 + n * 16 + (lane & 15);
                int chunk = (ks * 4 + (lane >> 4)) ^ (row & 7);
                bF[n] = ldfrag(&Bs[row * 64 + chunk * 8]);
            }
            #pragma unroll
            for (int m = 0; m < 4; ++m)
                #pragma unroll
                for (int n = 0; n < 4; ++n)
                    acc[m][n] = __builtin_amdgcn_mfma_f32_16x16x32_bf16(
                        aF[m], bF[n], acc[m][n], 0, 0, 0);
        }
    }

    int   rowTok[4][4];
    float rowP[4][4];
    bool  rowV[4][4];
    #pragma unroll
    for (int m = 0; m < 4; ++m)
        #pragma unroll
        for (int r = 0; r < 4; ++r) {
            int row = wm * 64 + m * 16 + (lane >> 4) * 4 + r;
            int gIdx = g0 + tm * 128 + row;
            if (gIdx < g1) {
                int entry = perm[gIdx];
                rowTok[m][r] = entry >> 1;
                rowP[m][r]   = prob[entry];
                rowV[m][r]   = true;
            } else rowV[m][r] = false;
        }
    #pragma unroll
    for (int n = 0; n < 4; ++n) {
        int col = tn * 128 + wn * 64 + n * 16 + (lane & 15);
        float bias = be[e * OUT_DIM + col];
        #pragma unroll
        for (int m = 0; m < 4; ++m)
            #pragma unroll
            for (int r = 0; r < 4; ++r)
                if (rowV[m][r]) {
                    float v = acc[m][n][r] + bias;
                    atomicAdd(&out[(size_t)rowTok[m][r] * OUT_DIM + col],
                              rowP[m][r] * v);
                }
    }
}

// ---- launch ----------------------------------------------------------------
extern "C" void kernel_launch(void* const* d_in, const int* in_sizes, int n_in,
                              void* d_out, int out_size, void* d_ws, size_t ws_size,
                              hipStream_t stream) {
    const float* x  = (const float*)d_in[0];
    const float* Wg = (const float*)d_in[1];
    const float* bg = (const float*)d_in[2];
    const float* We = (const float*)d_in[3];
    const float* be = (const float*)d_in[4];
    float* out = (float*)d_out;

    const size_t WEB_BYTES = (size_t)NUM_EXPERTS * OUT_DIM * IN_DIM * 2;  // 32 MB
    const size_t XB_BYTES  = (size_t)BTOK * IN_DIM * 2;                   // 16 MB
    const size_t needFull  = WEB_BYTES + XB_BYTES + (1u << 20);
    bool full = ws_size >= needFull;

    char* w = (char*)d_ws;
    unsigned short* Web = nullptr;
    unsigned short* xb  = nullptr;
    if (full) {
        Web = (unsigned short*)w; w += WEB_BYTES;
        xb  = (unsigned short*)w; w += XB_BYTES;
    }
    int*   offsets     = (int*)w;    w += 128;
    int*   cursor      = (int*)w;    w += 64;
    int*   eidx        = (int*)w;    w += (size_t)NSLOT * 4;
    float* probArr     = (float*)w;  w += (size_t)NSLOT * 4;
    int*   perm        = (int*)w;    w += (size_t)NSLOT * 4;
    float* partialLoad = (float*)w;  w += 256 * NUM_EXPERTS * 4;
    int*   partialCnt  = (int*)w;    w += 256 * NUM_EXPERTS * 4;

    hipMemsetAsync(d_out, 0, (size_t)out_size * sizeof(float), stream);

    if (full)
        convert_we<<<NUM_EXPERTS * OUT_DIM * IN_DIM / (256 * 8), 256, 0, stream>>>(We, Web);

    gate_kernel<<<BTOK / 32, 256, 0, stream>>>(x, Wg, bg, eidx, probArr,
                                               partialLoad, partialCnt, xb);
    finalize_gate<<<1, 64, 0, stream>>>(offsets, cursor, partialLoad, partialCnt,
                                        BTOK / 32, out + (size_t)BTOK * OUT_DIM);
    scatter_kernel<<<BTOK / 256, 256, 0, stream>>>(eidx, cursor, perm);

    if (full) {
        expert_gemm_bf16<<<16384, 256, 0, stream>>>(xb, Web, be, perm, probArr,
                                                    offsets, out);
    } else {
        dim3 grid(OUT_DIM / 128, NSLOT / 128, NUM_EXPERTS);
        expert_gemm_f32<<<grid, 256, 0, stream>>>(x, We, be, perm, probArr,
                                                  offsets, out);
    }
}

// Round 3
// 155.950 us; speedup vs baseline: 2.9955x; 1.4658x over previous
//
#include <hip/hip_runtime.h>
#include <hip/hip_bf16.h>

#define NUM_EXPERTS 16
#define IN_DIM 1024
#define OUT_DIM 1024
#define BTOK 8192
#define NSLOT (2 * BTOK)
#define MAX_DESC 144   // sum_e ceil(ne/128) <= 16384/128 + 16

typedef __attribute__((ext_vector_type(4))) float f32x4;
typedef __attribute__((ext_vector_type(4))) int   i32x4;
typedef __attribute__((ext_vector_type(4))) unsigned short u16x4;
typedef __attribute__((ext_vector_type(8))) short short8;
typedef __attribute__((ext_vector_type(8))) __bf16 bf16x8;

// ---- helpers -------------------------------------------------------------

static __device__ inline unsigned short f2bf(float f) {
    union { float f; unsigned u; } v; v.f = f;
    unsigned u = v.u;
    unsigned r = (u + 0x7FFFu + ((u >> 16) & 1u)) >> 16;  // RNE
    return (unsigned short)r;
}

static __device__ inline float bf2f(unsigned short b) {
    union { unsigned u; float f; } v; v.u = ((unsigned)b) << 16;
    return v.f;
}

static __device__ inline short8 pack8(float4 a, float4 b) {
    short8 s;
    s[0] = (short)f2bf(a.x); s[1] = (short)f2bf(a.y);
    s[2] = (short)f2bf(a.z); s[3] = (short)f2bf(a.w);
    s[4] = (short)f2bf(b.x); s[5] = (short)f2bf(b.y);
    s[6] = (short)f2bf(b.z); s[7] = (short)f2bf(b.w);
    return s;
}

static __device__ inline bf16x8 ldfrag(const unsigned short* p) {
    i32x4 v = *(const i32x4*)p;                 // ds_read_b128
    return __builtin_bit_cast(bf16x8, v);
}

#define GLOAD_LDS16(g, l)                                                     \
    __builtin_amdgcn_global_load_lds(                                         \
        (const __attribute__((address_space(1))) void*)(g),                   \
        (__attribute__((address_space(3))) void*)(l), 16, 0, 0)

// ---- kernel 0: We f32 -> bf16 ---------------------------------------------
__global__ __launch_bounds__(256) void convert_we(
    const float* __restrict__ We, unsigned short* __restrict__ Web)
{
    size_t i = ((size_t)blockIdx.x * 256 + threadIdx.x) * 8;
    const float4* s = (const float4*)(We + i);
    float4 v0 = s[0], v1 = s[1];
    *(short8*)(Web + i) = pack8(v0, v1);
}

// ---- kernel 1: gating (+ x -> bf16 copy) -----------------------------------
__global__ __launch_bounds__(256) void gate_kernel(
    const float* __restrict__ x, const float* __restrict__ Wg,
    const float* __restrict__ bg,
    int* __restrict__ eidx, float* __restrict__ prob,
    float* __restrict__ partialLoad, int* __restrict__ partialCount,
    unsigned short* __restrict__ xb)
{
    __shared__ float sWg[NUM_EXPERTS * IN_DIM];   // 64 KB
    __shared__ float sBg[NUM_EXPERTS];
    __shared__ float sLoad[NUM_EXPERTS];
    __shared__ int   sCnt[NUM_EXPERTS];

    int tid = threadIdx.x;
    for (int i = tid; i < NUM_EXPERTS * IN_DIM / 4; i += 256)
        ((float4*)sWg)[i] = ((const float4*)Wg)[i];
    if (tid < NUM_EXPERTS) { sBg[tid] = bg[tid]; sLoad[tid] = 0.f; sCnt[tid] = 0; }
    __syncthreads();

    int lane = tid & 63;
    int wave = tid >> 6;
    const bool wb = (xb != nullptr);

    for (int i = 0; i < 8; ++i) {
        int t = blockIdx.x * 32 + wave * 8 + i;
        const float4* xr = (const float4*)(x + (size_t)t * IN_DIM);

        float acc[NUM_EXPERTS];
        #pragma unroll
        for (int e = 0; e < NUM_EXPERTS; ++e) acc[e] = 0.f;

        #pragma unroll
        for (int pass = 0; pass < 4; ++pass) {
            float4 xv = xr[pass * 64 + lane];
            if (wb) {
                u16x4 b;
                b[0] = f2bf(xv.x); b[1] = f2bf(xv.y);
                b[2] = f2bf(xv.z); b[3] = f2bf(xv.w);
                *(u16x4*)(xb + (size_t)t * IN_DIM + (pass * 64 + lane) * 4) = b;
            }
            int kb = pass * 256 + lane * 4;
            #pragma unroll
            for (int e = 0; e < NUM_EXPERTS; ++e) {
                float4 wv = *(const float4*)&sWg[e * IN_DIM + kb];
                acc[e] += xv.x * wv.x + xv.y * wv.y + xv.z * wv.z + xv.w * wv.w;
            }
        }
        #pragma unroll
        for (int e = 0; e < NUM_EXPERTS; ++e) {
            float v = acc[e];
            #pragma unroll
            for (int off = 32; off; off >>= 1) v += __shfl_xor(v, off);
            acc[e] = v;
        }
        if (lane == 0) {
            float v0 = -1e30f, v1 = -1e30f; int i0 = 0, i1 = 0;
            #pragma unroll
            for (int e = 0; e < NUM_EXPERTS; ++e) {
                float v = acc[e] + sBg[e];
                if (v > v0) { v1 = v0; i1 = i0; v0 = v; i0 = e; }
                else if (v > v1) { v1 = v; i1 = e; }
            }
            float t1 = expf(v1 - v0);           // v1 <= v0
            float inv = 1.f / (1.f + t1);
            float p0 = inv, p1 = t1 * inv;
            eidx[2 * t]     = i0;  eidx[2 * t + 1] = i1;
            prob[2 * t]     = p0;  prob[2 * t + 1] = p1;
            atomicAdd(&sCnt[i0], 1);
            atomicAdd(&sCnt[i1], 1);
            atomicAdd(&sLoad[i0], p0);
            atomicAdd(&sLoad[i1], p1);
        }
    }
    __syncthreads();
    if (tid < NUM_EXPERTS) {
        partialLoad[blockIdx.x * NUM_EXPERTS + tid]  = sLoad[tid];
        partialCount[blockIdx.x * NUM_EXPERTS + tid] = sCnt[tid];
    }
}

// ---- kernel 2: offsets + aux loss + tile-descriptor list -------------------
// 256 partial blocks; 256 threads: e = tid&15, part = tid>>4 covers 16 blocks
__global__ __launch_bounds__(256) void finalize_gate(
    int* __restrict__ offsets, int* __restrict__ cursor,
    const float* __restrict__ partialLoad, const int* __restrict__ partialCount,
    float* __restrict__ aux_out, int* __restrict__ descs)
{
    __shared__ float sL[256];
    __shared__ int   sC[256];
    int tid = threadIdx.x;
    int e = tid & 15, part = tid >> 4;
    float s = 0.f; int c = 0;
    #pragma unroll
    for (int b = 0; b < 16; ++b) {
        int blk = part * 16 + b;
        s += partialLoad[blk * NUM_EXPERTS + e];
        c += partialCount[blk * NUM_EXPERTS + e];
    }
    sL[tid] = s; sC[tid] = c;
    __syncthreads();
    if (tid < NUM_EXPERTS) {
        float sum = 0.f; int cc = 0;
        #pragma unroll
        for (int p = 0; p < 16; ++p) { sum += sL[p * 16 + tid]; cc += sC[p * 16 + tid]; }
        sL[tid] = sum; sC[tid] = cc;
    }
    __syncthreads();
    if (tid == 0) {
        int off = 0, n = 0;
        for (int e2 = 0; e2 < NUM_EXPERTS; ++e2) {
            offsets[e2] = off; cursor[e2] = off;
            int ne = sC[e2];
            int ntm = (ne + 127) >> 7;
            for (int tm = 0; tm < ntm; ++tm) descs[1 + n++] = (e2 << 8) | tm;
            off += ne;
        }
        offsets[NUM_EXPERTS] = off;
        descs[0] = n;
        float mean = 0.f;
        for (int e2 = 0; e2 < NUM_EXPERTS; ++e2) mean += sL[e2];
        mean *= (1.f / NUM_EXPERTS);
        float var = 0.f;
        for (int e2 = 0; e2 < NUM_EXPERTS; ++e2) {
            float d = sL[e2] - mean; var += d * d;
        }
        var *= (1.f / (NUM_EXPERTS - 1));       // ddof=1
        aux_out[0] = sqrtf(var) / mean;
    }
}

// ---- kernel 3: counting-sort scatter --------------------------------------
__global__ __launch_bounds__(256) void scatter_kernel(
    const int* __restrict__ eidx, int* __restrict__ cursor,
    int* __restrict__ perm)
{
    __shared__ int lc[NUM_EXPERTS];
    __shared__ int lbase[NUM_EXPERTS];
    int tid = threadIdx.x;
    if (tid < NUM_EXPERTS) lc[tid] = 0;
    __syncthreads();
    int t = blockIdx.x * 256 + tid;
    int e0 = eidx[2 * t], e1 = eidx[2 * t + 1];
    int lp0 = atomicAdd(&lc[e0], 1);
    int lp1 = atomicAdd(&lc[e1], 1);
    __syncthreads();
    if (tid < NUM_EXPERTS) lbase[tid] = atomicAdd(&cursor[tid], lc[tid]);
    __syncthreads();
    perm[lbase[e0] + lp0] = 2 * t;
    perm[lbase[e1] + lp1] = 2 * t + 1;
}

// ---- kernel 4: bf16 grouped GEMM, dbuf LDS, atomic-free y2 epilogue --------
// grid fixed 144*8; block -> (desc d = bid>>3, tn = bid&7); tn == XCD id
// y2[entry][col] bf16, entry = perm[g] = 2*token+k; y2 aliases d_out exactly.
__global__ __launch_bounds__(256) void expert_gemm_bf16(
    const unsigned short* __restrict__ xb, const unsigned short* __restrict__ Web,
    const int* __restrict__ perm, const int* __restrict__ offsets,
    const int* __restrict__ descs, unsigned short* __restrict__ y2)
{
    int d  = blockIdx.x >> 3;
    int tn = blockIdx.x & 7;
    if (d >= descs[0]) return;
    int de = descs[1 + d];
    int e = de >> 8, tm = de & 255;
    int g0 = offsets[e], g1 = offsets[e + 1];

    __shared__ unsigned short As[2][128 * 64];   // 2 x 16 KB
    __shared__ unsigned short Bs[2][128 * 64];   // 2 x 16 KB

    int tid = threadIdx.x, lane = tid & 63, w = tid >> 6;
    int wm = w >> 1, wn = w & 1;

    // staging: chunk c = 256*i + 64*w + lane; LDS slot (row=c>>3, ss=c&7);
    // pre-swizzled global source chunk s = ss ^ (row&7); reads undo the XOR.
    const char* aPtr[4];
    const char* bPtr[4];
    #pragma unroll
    for (int i = 0; i < 4; ++i) {
        int c = 256 * i + 64 * w + lane;
        int row = c >> 3, ss = c & 7;
        int s = ss ^ (row & 7);
        int gIdx = g0 + tm * 128 + row;
        if (gIdx > NSLOT - 1) gIdx = NSLOT - 1;         // clamp; masked at store
        int tok = perm[gIdx] >> 1;
        aPtr[i] = (const char*)(xb + (size_t)tok * IN_DIM + s * 8);
        bPtr[i] = (const char*)(Web + ((size_t)e * OUT_DIM + tn * 128 + row) * IN_DIM + s * 8);
    }

    f32x4 acc[4][4];
    #pragma unroll
    for (int m = 0; m < 4; ++m)
        #pragma unroll
        for (int n = 0; n < 4; ++n) {
            acc[m][n][0] = 0.f; acc[m][n][1] = 0.f;
            acc[m][n][2] = 0.f; acc[m][n][3] = 0.f;
        }

    // prologue: stage K-tile 0 into buffer 0
    #pragma unroll
    for (int i = 0; i < 4; ++i)
        GLOAD_LDS16(aPtr[i], &As[0][(256 * i + 64 * w) * 8]);
    #pragma unroll
    for (int i = 0; i < 4; ++i)
        GLOAD_LDS16(bPtr[i], &Bs[0][(256 * i + 64 * w) * 8]);
    __syncthreads();

    int cur = 0;
    for (int t = 0; t < IN_DIM / 64; ++t) {
        // issue next-tile loads into the other buffer (overlaps MFMA below)
        if (t < IN_DIM / 64 - 1) {
            int kByte = (t + 1) * 64 * 2;
            #pragma unroll
            for (int i = 0; i < 4; ++i)
                GLOAD_LDS16(aPtr[i] + kByte, &As[cur ^ 1][(256 * i + 64 * w) * 8]);
            #pragma unroll
            for (int i = 0; i < 4; ++i)
                GLOAD_LDS16(bPtr[i] + kByte, &Bs[cur ^ 1][(256 * i + 64 * w) * 8]);
        }
        // compute current buffer
        #pragma unroll
        for (int ks = 0; ks < 2; ++ks) {
            bf16x8 aF[4], bF[4];
            #pragma unroll
            for (int m = 0; m < 4; ++m) {
                int row = wm * 64 + m * 16 + (lane & 15);
                int chunk = (ks * 4 + (lane >> 4)) ^ (row & 7);
                aF[m] = ldfrag(&As[cur][row * 64 + chunk * 8]);
            }
            #pragma unroll
            for (int n = 0; n < 4; ++n) {
                int row = wn * 64 + n * 16 + (lane & 15);
                int chunk = (ks * 4 + (lane >> 4)) ^ (row & 7);
                bF[n] = ldfrag(&Bs[cur][row * 64 + chunk * 8]);
            }
            #pragma unroll
            for (int m = 0; m < 4; ++m)
                #pragma unroll
                for (int n = 0; n < 4; ++n)
                    acc[m][n] = __builtin_amdgcn_mfma_f32_16x16x32_bf16(
                        aF[m], bF[n], acc[m][n], 0, 0, 0);
        }
        __syncthreads();   // drains vmcnt(0): next buffer staged; reads done
        cur ^= 1;
    }

    // epilogue: plain bf16 stores, y2[entry][col] = acc  (no atomics)
    int  rowEnt[4][4];
    bool rowV[4][4];
    #pragma unroll
    for (int m = 0; m < 4; ++m)
        #pragma unroll
        for (int r = 0; r < 4; ++r) {
            int row = wm * 64 + m * 16 + (lane >> 4) * 4 + r;
            int gIdx = g0 + tm * 128 + row;
            if (gIdx < g1) { rowEnt[m][r] = perm[gIdx]; rowV[m][r] = true; }
            else rowV[m][r] = false;
        }
    #pragma unroll
    for (int n = 0; n < 4; ++n) {
        int col = tn * 128 + wn * 64 + n * 16 + (lane & 15);
        #pragma unroll
        for (int m = 0; m < 4; ++m)
            #pragma unroll
            for (int r = 0; r < 4; ++r)
                if (rowV[m][r])
                    y2[(size_t)rowEnt[m][r] * OUT_DIM + col] = f2bf(acc[m][n][r]);
    }
}

// ---- kernel 5: in-place combine -------------------------------------------
// out row t (f32, 4 KB) aliases y2 rows 2t (first 2 KB) and 2t+1 (second 2 KB).
// Read both slot rows -> barrier -> overwrite with weighted sum + bias.
__global__ __launch_bounds__(256) void combine_kernel(
    float* __restrict__ out, const int* __restrict__ eidx,
    const float* __restrict__ prob, const float* __restrict__ be)
{
    int t   = blockIdx.x;
    int tid = threadIdx.x;
    int e0 = eidx[2 * t], e1 = eidx[2 * t + 1];
    float p0 = prob[2 * t], p1 = prob[2 * t + 1];

    const unsigned short* y = (const unsigned short*)out;
    u16x4 a = *(const u16x4*)(y + (size_t)(2 * t)     * OUT_DIM + tid * 4);
    u16x4 b = *(const u16x4*)(y + (size_t)(2 * t + 1) * OUT_DIM + tid * 4);
    float4 b0 = *(const float4*)(be + e0 * OUT_DIM + tid * 4);
    float4 b1 = *(const float4*)(be + e1 * OUT_DIM + tid * 4);

    float4 r;
    r.x = p0 * (bf2f(a[0]) + b0.x) + p1 * (bf2f(b[0]) + b1.x);
    r.y = p0 * (bf2f(a[1]) + b0.y) + p1 * (bf2f(b[1]) + b1.y);
    r.z = p0 * (bf2f(a[2]) + b0.z) + p1 * (bf2f(b[2]) + b1.z);
    r.w = p0 * (bf2f(a[3]) + b0.w) + p1 * (bf2f(b[3]) + b1.w);

    __syncthreads();   // all reads of this row complete before overwrite
    *(float4*)(out + (size_t)t * OUT_DIM + tid * 4) = r;
}

// ---- fallback: f32-input grouped GEMM with atomic epilogue (proven) --------
__global__ __launch_bounds__(256) void expert_gemm_f32(
    const float* __restrict__ x, const float* __restrict__ We,
    const float* __restrict__ be,
    const int* __restrict__ perm, const float* __restrict__ prob,
    const int* __restrict__ offsets, float* __restrict__ out)
{
    int e  = blockIdx.z;
    int g0 = offsets[e], g1 = offsets[e + 1];
    int ne = g1 - g0;
    int tm = blockIdx.y;
    if (tm * 128 >= ne) return;
    int tn = blockIdx.x;

    __shared__ unsigned short As[128 * 64];
    __shared__ unsigned short Bs[128 * 64];

    int tid  = threadIdx.x;
    int lane = tid & 63;
    int wave = tid >> 6;
    int wm = wave >> 1, wn = wave & 1;

    const float* aSrc[4]; bool aValid[4];
    #pragma unroll
    for (int i = 0; i < 4; ++i) {
        int c = tid + 256 * i;
        int row = c >> 3;
        int gIdx = g0 + tm * 128 + row;
        if (gIdx < g1) {
            int tok = perm[gIdx] >> 1;
            aSrc[i] = x + (size_t)tok * IN_DIM;
            aValid[i] = true;
        } else { aSrc[i] = x; aValid[i] = false; }
    }
    const float* bSrcBase = We + (size_t)e * OUT_DIM * IN_DIM;

    f32x4 acc[4][4];
    #pragma unroll
    for (int m = 0; m < 4; ++m)
        #pragma unroll
        for (int n = 0; n < 4; ++n) {
            acc[m][n][0] = 0.f; acc[m][n][1] = 0.f;
            acc[m][n][2] = 0.f; acc[m][n][3] = 0.f;
        }

    for (int k0 = 0; k0 < IN_DIM; k0 += 64) {
        __syncthreads();
        #pragma unroll
        for (int i = 0; i < 4; ++i) {
            int c = tid + 256 * i;
            int row = c >> 3, s = c & 7;
            float4 v0, v1;
            if (aValid[i]) {
                const float* p = aSrc[i] + k0 + s * 8;
                v0 = *(const float4*)p;
                v1 = *(const float4*)(p + 4);
            } else {
                v0 = make_float4(0.f, 0.f, 0.f, 0.f); v1 = v0;
            }
            int ss = s ^ (row & 7);
            *(short8*)&As[row * 64 + ss * 8] = pack8(v0, v1);
        }
        #pragma unroll
        for (int i = 0; i < 4; ++i) {
            int c = tid + 256 * i;
            int row = c >> 3, s = c & 7;
            int o = tn * 128 + row;
            const float* p = bSrcBase + (size_t)o * IN_DIM + k0 + s * 8;
            float4 v0 = *(const float4*)p;
            float4 v1 = *(const float4*)(p + 4);
            int ss = s ^ (row & 7);
            *(short8*)&Bs[row * 64 + ss * 8] = pack8(v0, v1);
        }
        __syncthreads();

        #pragma unroll
        for (int ks = 0; ks < 2; ++ks) {
            bf16x8 aF[4], bF[4];
            #pragma unroll
            for (int m = 0; m < 4; ++m) {
                int row = wm * 64 + m * 16 + (lane & 15);
                int chunk = (ks * 4 + (lane >> 4)) ^ (row & 7);
                aF[m] = ldfrag(&As[row * 64 + chunk * 8]);
            }
            #pragma unroll
            for (int n = 0; n < 4; ++n) {
                int row = wn * 64 + n * 16 + (lane & 15);
                int chunk = (ks * 4 + (lane >> 4)) ^ (row & 7);
                bF[n] = ldfrag(&Bs[row * 64 + chunk * 8]);
            }
            #pragma unroll
            for (int m = 0; m < 4; ++m)
                #pragma unroll
                for (int n = 0; n < 4; ++n)
                    acc[m][n] = __builtin_amdgcn_mfma_f32_16x16x32_bf16(
                        aF[m], bF[n], acc[m][n], 0, 0, 0);
        }
    }

    int   rowTok[4][4];
    float rowP[4][4];
    bool  rowV[4][4];
    #pragma unroll
    for (int m = 0; m < 4; ++m)
        #pragma unroll
        for (int r = 0; r < 4; ++r) {
            int row = wm * 64 + m * 16 + (lane >> 4) * 4 + r;
            int gIdx = g0 + tm * 128 + row;
            if (gIdx < g1) {
                int entry = perm[gIdx];
                rowTok[m][r] = entry >> 1;
                rowP[m][r]   = prob[entry];
                rowV[m][r]   = true;
            } else rowV[m][r] = false;
        }
    #pragma unroll
    for (int n = 0; n < 4; ++n) {
        int col = tn * 128 + wn * 64 + n * 16 + (lane & 15);
        float bias = be[e * OUT_DIM + col];
        #pragma unroll
        for (int m = 0; m < 4; ++m)
            #pragma unroll
            for (int r = 0; r < 4; ++r)
                if (rowV[m][r]) {
                    float v = acc[m][n][r] + bias;
                    atomicAdd(&out[(size_t)rowTok[m][r] * OUT_DIM + col],
                              rowP[m][r] * v);
                }
    }
}

// ---- launch ----------------------------------------------------------------
extern "C" void kernel_launch(void* const* d_in, const int* in_sizes, int n_in,
                              void* d_out, int out_size, void* d_ws, size_t ws_size,
                              hipStream_t stream) {
    const float* x  = (const float*)d_in[0];
    const float* Wg = (const float*)d_in[1];
    const float* bg = (const float*)d_in[2];
    const float* We = (const float*)d_in[3];
    const float* be = (const float*)d_in[4];
    float* out = (float*)d_out;

    const size_t WEB_BYTES = (size_t)NUM_EXPERTS * OUT_DIM * IN_DIM * 2;  // 32 MB
    const size_t XB_BYTES  = (size_t)BTOK * IN_DIM * 2;                   // 16 MB
    const size_t MISC      = (size_t)NSLOT * 12 + 256 * NUM_EXPERTS * 8 + 4096;
    bool full = ws_size >= WEB_BYTES + XB_BYTES + MISC;

    char* w = (char*)d_ws;
    unsigned short* Web = nullptr;
    unsigned short* xb  = nullptr;
    if (full) {
        Web = (unsigned short*)w; w += WEB_BYTES;
        xb  = (unsigned short*)w; w += XB_BYTES;
    }
    int*   offsets     = (int*)w;    w += 128;
    int*   cursor      = (int*)w;    w += 64;
    int*   descs       = (int*)w;    w += (1 + MAX_DESC) * 4 + 60;
    int*   eidx        = (int*)w;    w += (size_t)NSLOT * 4;
    float* probArr     = (float*)w;  w += (size_t)NSLOT * 4;
    int*   perm        = (int*)w;    w += (size_t)NSLOT * 4;
    float* partialLoad = (float*)w;  w += 256 * NUM_EXPERTS * 4;
    int*   partialCnt  = (int*)w;    w += 256 * NUM_EXPERTS * 4;

    if (full)
        convert_we<<<NUM_EXPERTS * OUT_DIM * IN_DIM / (256 * 8), 256, 0, stream>>>(We, Web);
    else
        hipMemsetAsync(d_out, 0, (size_t)out_size * sizeof(float), stream);

    gate_kernel<<<BTOK / 32, 256, 0, stream>>>(x, Wg, bg, eidx, probArr,
                                               partialLoad, partialCnt,
                                               full ? xb : nullptr);
    finalize_gate<<<1, 256, 0, stream>>>(offsets, cursor, partialLoad, partialCnt,
                                         out + (size_t)BTOK * OUT_DIM, descs);
    scatter_kernel<<<BTOK / 256, 256, 0, stream>>>(eidx, cursor, perm);

    if (full) {
        expert_gemm_bf16<<<MAX_DESC * 8, 256, 0, stream>>>(
            xb, Web, perm, offsets, descs, (unsigned short*)d_out);
        combine_kernel<<<BTOK, 256, 0, stream>>>(out, eidx, probArr, be);
    } else {
        dim3 grid(OUT_DIM / 128, NSLOT / 128, NUM_EXPERTS);
        expert_gemm_f32<<<grid, 256, 0, stream>>>(x, We, be, perm, probArr,
                                                  offsets, out);
    }
}

// Round 4
// 152.998 us; speedup vs baseline: 3.0533x; 1.0193x over previous
//
#include <hip/hip_runtime.h>
#include <hip/hip_bf16.h>

#define NUM_EXPERTS 16
#define IN_DIM 1024
#define OUT_DIM 1024
#define BTOK 8192
#define NSLOT (2 * BTOK)
#define MAX_DESC 144   // sum_e ceil(ne/128) <= 16384/128 + 16

typedef __attribute__((ext_vector_type(4))) float f32x4;
typedef __attribute__((ext_vector_type(4))) int   i32x4;
typedef __attribute__((ext_vector_type(4))) unsigned short u16x4;
typedef __attribute__((ext_vector_type(8))) short short8;
typedef __attribute__((ext_vector_type(8))) __bf16 bf16x8;

// ---- helpers -------------------------------------------------------------

static __device__ inline unsigned short f2bf(float f) {
    union { float f; unsigned u; } v; v.f = f;
    unsigned u = v.u;
    unsigned r = (u + 0x7FFFu + ((u >> 16) & 1u)) >> 16;  // RNE
    return (unsigned short)r;
}

static __device__ inline float bf2f(unsigned short b) {
    union { unsigned u; float f; } v; v.u = ((unsigned)b) << 16;
    return v.f;
}

static __device__ inline short8 pack8(float4 a, float4 b) {
    short8 s;
    s[0] = (short)f2bf(a.x); s[1] = (short)f2bf(a.y);
    s[2] = (short)f2bf(a.z); s[3] = (short)f2bf(a.w);
    s[4] = (short)f2bf(b.x); s[5] = (short)f2bf(b.y);
    s[6] = (short)f2bf(b.z); s[7] = (short)f2bf(b.w);
    return s;
}

static __device__ inline bf16x8 ldfrag(const unsigned short* p) {
    i32x4 v = *(const i32x4*)p;                 // ds_read_b128
    return __builtin_bit_cast(bf16x8, v);
}

#define GLOAD_LDS16(g, l)                                                     \
    __builtin_amdgcn_global_load_lds(                                         \
        (const __attribute__((address_space(1))) void*)(g),                   \
        (__attribute__((address_space(3))) void*)(l), 16, 0, 0)

// ---- kernel 1: gating + x->bf16 + We->bf16 (fused streaming) ---------------
// grid: 256 blocks x 256 threads; each block = 4 waves x 8 tokens = 32 tokens
// Each block also converts 65536 elements of We (16.78M / 256).
__global__ __launch_bounds__(256) void gate_kernel(
    const float* __restrict__ x, const float* __restrict__ Wg,
    const float* __restrict__ bg,
    int* __restrict__ eidx, float* __restrict__ prob,
    float* __restrict__ partialLoad, int* __restrict__ partialCount,
    unsigned short* __restrict__ xb,
    const float* __restrict__ We, unsigned short* __restrict__ Web)
{
    __shared__ float sWg[NUM_EXPERTS * IN_DIM];   // 64 KB
    __shared__ float sBg[NUM_EXPERTS];
    __shared__ float sLoad[NUM_EXPERTS];
    __shared__ int   sCnt[NUM_EXPERTS];

    int tid = threadIdx.x;
    for (int i = tid; i < NUM_EXPERTS * IN_DIM / 4; i += 256)
        ((float4*)sWg)[i] = ((const float4*)Wg)[i];
    if (tid < NUM_EXPERTS) { sBg[tid] = bg[tid]; sLoad[tid] = 0.f; sCnt[tid] = 0; }

    // fused We -> bf16 conversion (streaming; hides under gate VALU work)
    if (Web != nullptr) {
        size_t base = (size_t)blockIdx.x * 65536;
        #pragma unroll 4
        for (int i = 0; i < 32; ++i) {
            size_t off = base + (size_t)(i * 256 + tid) * 8;
            const float4* s = (const float4*)(We + off);
            float4 v0 = s[0], v1 = s[1];
            *(short8*)(Web + off) = pack8(v0, v1);
        }
    }
    __syncthreads();

    int lane = tid & 63;
    int wave = tid >> 6;
    const bool wb = (xb != nullptr);

    for (int i = 0; i < 8; ++i) {
        int t = blockIdx.x * 32 + wave * 8 + i;
        const float4* xr = (const float4*)(x + (size_t)t * IN_DIM);

        float acc[NUM_EXPERTS];
        #pragma unroll
        for (int e = 0; e < NUM_EXPERTS; ++e) acc[e] = 0.f;

        #pragma unroll
        for (int pass = 0; pass < 4; ++pass) {
            float4 xv = xr[pass * 64 + lane];
            if (wb) {
                u16x4 b;
                b[0] = f2bf(xv.x); b[1] = f2bf(xv.y);
                b[2] = f2bf(xv.z); b[3] = f2bf(xv.w);
                *(u16x4*)(xb + (size_t)t * IN_DIM + (pass * 64 + lane) * 4) = b;
            }
            int kb = pass * 256 + lane * 4;
            #pragma unroll
            for (int e = 0; e < NUM_EXPERTS; ++e) {
                float4 wv = *(const float4*)&sWg[e * IN_DIM + kb];
                acc[e] += xv.x * wv.x + xv.y * wv.y + xv.z * wv.z + xv.w * wv.w;
            }
        }
        #pragma unroll
        for (int e = 0; e < NUM_EXPERTS; ++e) {
            float v = acc[e];
            #pragma unroll
            for (int off = 32; off; off >>= 1) v += __shfl_xor(v, off);
            acc[e] = v;
        }
        if (lane == 0) {
            float v0 = -1e30f, v1 = -1e30f; int i0 = 0, i1 = 0;
            #pragma unroll
            for (int e = 0; e < NUM_EXPERTS; ++e) {
                float v = acc[e] + sBg[e];
                if (v > v0) { v1 = v0; i1 = i0; v0 = v; i0 = e; }
                else if (v > v1) { v1 = v; i1 = e; }
            }
            float t1 = expf(v1 - v0);           // v1 <= v0
            float inv = 1.f / (1.f + t1);
            float p0 = inv, p1 = t1 * inv;
            eidx[2 * t]     = i0;  eidx[2 * t + 1] = i1;
            prob[2 * t]     = p0;  prob[2 * t + 1] = p1;
            atomicAdd(&sCnt[i0], 1);
            atomicAdd(&sCnt[i1], 1);
            atomicAdd(&sLoad[i0], p0);
            atomicAdd(&sLoad[i1], p1);
        }
    }
    __syncthreads();
    if (tid < NUM_EXPERTS) {
        partialLoad[blockIdx.x * NUM_EXPERTS + tid]  = sLoad[tid];
        partialCount[blockIdx.x * NUM_EXPERTS + tid] = sCnt[tid];
    }
}

// ---- kernel 2: offsets + aux loss + tile-descriptor list -------------------
__global__ __launch_bounds__(256) void finalize_gate(
    int* __restrict__ offsets, int* __restrict__ cursor,
    const float* __restrict__ partialLoad, const int* __restrict__ partialCount,
    float* __restrict__ aux_out, int* __restrict__ descs)
{
    __shared__ float sL[256];
    __shared__ int   sC[256];
    int tid = threadIdx.x;
    int e = tid & 15, part = tid >> 4;
    float s = 0.f; int c = 0;
    #pragma unroll
    for (int b = 0; b < 16; ++b) {
        int blk = part * 16 + b;
        s += partialLoad[blk * NUM_EXPERTS + e];
        c += partialCount[blk * NUM_EXPERTS + e];
    }
    sL[tid] = s; sC[tid] = c;
    __syncthreads();
    if (tid < NUM_EXPERTS) {
        float sum = 0.f; int cc = 0;
        #pragma unroll
        for (int p = 0; p < 16; ++p) { sum += sL[p * 16 + tid]; cc += sC[p * 16 + tid]; }
        sL[tid] = sum; sC[tid] = cc;
    }
    __syncthreads();
    if (tid == 0) {
        int off = 0, n = 0;
        for (int e2 = 0; e2 < NUM_EXPERTS; ++e2) {
            offsets[e2] = off; cursor[e2] = off;
            int ne = sC[e2];
            int ntm = (ne + 127) >> 7;
            for (int tm = 0; tm < ntm; ++tm) descs[1 + n++] = (e2 << 8) | tm;
            off += ne;
        }
        offsets[NUM_EXPERTS] = off;
        descs[0] = n;
        float mean = 0.f;
        for (int e2 = 0; e2 < NUM_EXPERTS; ++e2) mean += sL[e2];
        mean *= (1.f / NUM_EXPERTS);
        float var = 0.f;
        for (int e2 = 0; e2 < NUM_EXPERTS; ++e2) {
            float d = sL[e2] - mean; var += d * d;
        }
        var *= (1.f / (NUM_EXPERTS - 1));       // ddof=1
        aux_out[0] = sqrtf(var) / mean;
    }
}

// ---- kernel 3: counting-sort scatter --------------------------------------
__global__ __launch_bounds__(256) void scatter_kernel(
    const int* __restrict__ eidx, int* __restrict__ cursor,
    int* __restrict__ perm)
{
    __shared__ int lc[NUM_EXPERTS];
    __shared__ int lbase[NUM_EXPERTS];
    int tid = threadIdx.x;
    if (tid < NUM_EXPERTS) lc[tid] = 0;
    __syncthreads();
    int t = blockIdx.x * 256 + tid;
    int e0 = eidx[2 * t], e1 = eidx[2 * t + 1];
    int lp0 = atomicAdd(&lc[e0], 1);
    int lp1 = atomicAdd(&lc[e1], 1);
    __syncthreads();
    if (tid < NUM_EXPERTS) lbase[tid] = atomicAdd(&cursor[tid], lc[tid]);
    __syncthreads();
    perm[lbase[e0] + lp0] = 2 * t;
    perm[lbase[e1] + lp1] = 2 * t + 1;
}

// ---- kernel 4: bf16 grouped GEMM, single-buffer m97 structure --------------
// grid fixed 144*8; block -> (desc d = bid>>3, tn = bid&7); tn == XCD id
// y2[entry][col] bf16, entry = perm[g] = 2*token+k; y2 aliases d_out exactly.
__global__ __launch_bounds__(256) void expert_gemm_bf16(
    const unsigned short* __restrict__ xb, const unsigned short* __restrict__ Web,
    const int* __restrict__ perm, const int* __restrict__ offsets,
    const int* __restrict__ descs, unsigned short* __restrict__ y2)
{
    int d  = blockIdx.x >> 3;
    int tn = blockIdx.x & 7;
    if (d >= descs[0]) return;
    int de = descs[1 + d];
    int e = de >> 8, tm = de & 255;
    int g0 = offsets[e], g1 = offsets[e + 1];

    __shared__ unsigned short As[128 * 64];   // 16 KB (single buffer: 5 blk/CU)
    __shared__ unsigned short Bs[128 * 64];   // 16 KB

    int tid = threadIdx.x, lane = tid & 63, w = tid >> 6;
    int wm = w >> 1, wn = w & 1;

    // staging: chunk c = 256*i + 64*w + lane; LDS slot (row=c>>3, ss=c&7);
    // pre-swizzled global source chunk s = ss ^ (row&7); reads undo the XOR.
    const char* aPtr[4];
    const char* bPtr[4];
    #pragma unroll
    for (int i = 0; i < 4; ++i) {
        int c = 256 * i + 64 * w + lane;
        int row = c >> 3, ss = c & 7;
        int s = ss ^ (row & 7);
        int gIdx = g0 + tm * 128 + row;
        if (gIdx > NSLOT - 1) gIdx = NSLOT - 1;         // clamp; masked at store
        int tok = perm[gIdx] >> 1;
        aPtr[i] = (const char*)(xb + (size_t)tok * IN_DIM + s * 8);
        bPtr[i] = (const char*)(Web + ((size_t)e * OUT_DIM + tn * 128 + row) * IN_DIM + s * 8);
    }

    f32x4 acc[4][4];
    #pragma unroll
    for (int m = 0; m < 4; ++m)
        #pragma unroll
        for (int n = 0; n < 4; ++n) {
            acc[m][n][0] = 0.f; acc[m][n][1] = 0.f;
            acc[m][n][2] = 0.f; acc[m][n][3] = 0.f;
        }

    for (int k0 = 0; k0 < IN_DIM; k0 += 64) {
        __syncthreads();   // prev-tile ds_reads complete before overwrite
        #pragma unroll
        for (int i = 0; i < 4; ++i)
            GLOAD_LDS16(aPtr[i] + k0 * 2, &As[(256 * i + 64 * w) * 8]);
        #pragma unroll
        for (int i = 0; i < 4; ++i)
            GLOAD_LDS16(bPtr[i] + k0 * 2, &Bs[(256 * i + 64 * w) * 8]);
        __syncthreads();   // compiler drains vmcnt(0): tile staged

        #pragma unroll
        for (int ks = 0; ks < 2; ++ks) {
            bf16x8 aF[4], bF[4];
            #pragma unroll
            for (int m = 0; m < 4; ++m) {
                int row = wm * 64 + m * 16 + (lane & 15);
                int chunk = (ks * 4 + (lane >> 4)) ^ (row & 7);
                aF[m] = ldfrag(&As[row * 64 + chunk * 8]);
            }
            #pragma unroll
            for (int n = 0; n < 4; ++n) {
                int row = wn * 64 + n * 16 + (lane & 15);
                int chunk = (ks * 4 + (lane >> 4)) ^ (row & 7);
                bF[n] = ldfrag(&Bs[row * 64 + chunk * 8]);
            }
            #pragma unroll
            for (int m = 0; m < 4; ++m)
                #pragma unroll
                for (int n = 0; n < 4; ++n)
                    acc[m][n] = __builtin_amdgcn_mfma_f32_16x16x32_bf16(
                        aF[m], bF[n], acc[m][n], 0, 0, 0);
        }
    }

    // epilogue: plain bf16 stores, y2[entry][col] = acc  (no atomics)
    int  rowEnt[4][4];
    bool rowV[4][4];
    #pragma unroll
    for (int m = 0; m < 4; ++m)
        #pragma unroll
        for (int r = 0; r < 4; ++r) {
            int row = wm * 64 + m * 16 + (lane >> 4) * 4 + r;
            int gIdx = g0 + tm * 128 + row;
            if (gIdx < g1) { rowEnt[m][r] = perm[gIdx]; rowV[m][r] = true; }
            else rowV[m][r] = false;
        }
    #pragma unroll
    for (int n = 0; n < 4; ++n) {
        int col = tn * 128 + wn * 64 + n * 16 + (lane & 15);
        #pragma unroll
        for (int m = 0; m < 4; ++m)
            #pragma unroll
            for (int r = 0; r < 4; ++r)
                if (rowV[m][r])
                    y2[(size_t)rowEnt[m][r] * OUT_DIM + col] = f2bf(acc[m][n][r]);
    }
}

// ---- kernel 5: in-place combine -------------------------------------------
// out row t (f32, 4 KB) aliases y2 rows 2t (first 2 KB) and 2t+1 (second 2 KB).
__global__ __launch_bounds__(256) void combine_kernel(
    float* __restrict__ out, const int* __restrict__ eidx,
    const float* __restrict__ prob, const float* __restrict__ be)
{
    int t   = blockIdx.x;
    int tid = threadIdx.x;
    int e0 = eidx[2 * t], e1 = eidx[2 * t + 1];
    float p0 = prob[2 * t], p1 = prob[2 * t + 1];

    const unsigned short* y = (const unsigned short*)out;
    u16x4 a = *(const u16x4*)(y + (size_t)(2 * t)     * OUT_DIM + tid * 4);
    u16x4 b = *(const u16x4*)(y + (size_t)(2 * t + 1) * OUT_DIM + tid * 4);
    float4 b0 = *(const float4*)(be + e0 * OUT_DIM + tid * 4);
    float4 b1 = *(const float4*)(be + e1 * OUT_DIM + tid * 4);

    float4 r;
    r.x = p0 * (bf2f(a[0]) + b0.x) + p1 * (bf2f(b[0]) + b1.x);
    r.y = p0 * (bf2f(a[1]) + b0.y) + p1 * (bf2f(b[1]) + b1.y);
    r.z = p0 * (bf2f(a[2]) + b0.z) + p1 * (bf2f(b[2]) + b1.z);
    r.w = p0 * (bf2f(a[3]) + b0.w) + p1 * (bf2f(b[3]) + b1.w);

    __syncthreads();   // all reads of this row complete before overwrite
    *(float4*)(out + (size_t)t * OUT_DIM + tid * 4) = r;
}

// ---- fallback: f32-input grouped GEMM with atomic epilogue (proven) --------
__global__ __launch_bounds__(256) void expert_gemm_f32(
    const float* __restrict__ x, const float* __restrict__ We,
    const float* __restrict__ be,
    const int* __restrict__ perm, const float* __restrict__ prob,
    const int* __restrict__ offsets, float* __restrict__ out)
{
    int e  = blockIdx.z;
    int g0 = offsets[e], g1 = offsets[e + 1];
    int ne = g1 - g0;
    int tm = blockIdx.y;
    if (tm * 128 >= ne) return;
    int tn = blockIdx.x;

    __shared__ unsigned short As[128 * 64];
    __shared__ unsigned short Bs[128 * 64];

    int tid  = threadIdx.x;
    int lane = tid & 63;
    int wave = tid >> 6;
    int wm = wave >> 1, wn = wave & 1;

    const float* aSrc[4]; bool aValid[4];
    #pragma unroll
    for (int i = 0; i < 4; ++i) {
        int c = tid + 256 * i;
        int row = c >> 3;
        int gIdx = g0 + tm * 128 + row;
        if (gIdx < g1) {
            int tok = perm[gIdx] >> 1;
            aSrc[i] = x + (size_t)tok * IN_DIM;
            aValid[i] = true;
        } else { aSrc[i] = x; aValid[i] = false; }
    }
    const float* bSrcBase = We + (size_t)e * OUT_DIM * IN_DIM;

    f32x4 acc[4][4];
    #pragma unroll
    for (int m = 0; m < 4; ++m)
        #pragma unroll
        for (int n = 0; n < 4; ++n) {
            acc[m][n][0] = 0.f; acc[m][n][1] = 0.f;
            acc[m][n][2] = 0.f; acc[m][n][3] = 0.f;
        }

    for (int k0 = 0; k0 < IN_DIM; k0 += 64) {
        __syncthreads();
        #pragma unroll
        for (int i = 0; i < 4; ++i) {
            int c = tid + 256 * i;
            int row = c >> 3, s = c & 7;
            float4 v0, v1;
            if (aValid[i]) {
                const float* p = aSrc[i] + k0 + s * 8;
                v0 = *(const float4*)p;
                v1 = *(const float4*)(p + 4);
            } else {
                v0 = make_float4(0.f, 0.f, 0.f, 0.f); v1 = v0;
            }
            int ss = s ^ (row & 7);
            *(short8*)&As[row * 64 + ss * 8] = pack8(v0, v1);
        }
        #pragma unroll
        for (int i = 0; i < 4; ++i) {
            int c = tid + 256 * i;
            int row = c >> 3, s = c & 7;
            int o = tn * 128 + row;
            const float* p = bSrcBase + (size_t)o * IN_DIM + k0 + s * 8;
            float4 v0 = *(const float4*)p;
            float4 v1 = *(const float4*)(p + 4);
            int ss = s ^ (row & 7);
            *(short8*)&Bs[row * 64 + ss * 8] = pack8(v0, v1);
        }
        __syncthreads();

        #pragma unroll
        for (int ks = 0; ks < 2; ++ks) {
            bf16x8 aF[4], bF[4];
            #pragma unroll
            for (int m = 0; m < 4; ++m) {
                int row = wm * 64 + m * 16 + (lane & 15);
                int chunk = (ks * 4 + (lane >> 4)) ^ (row & 7);
                aF[m] = ldfrag(&As[row * 64 + chunk * 8]);
            }
            #pragma unroll
            for (int n = 0; n < 4; ++n) {
                int row = wn * 64 + n * 16 + (lane & 15);
                int chunk = (ks * 4 + (lane >> 4)) ^ (row & 7);
                bF[n] = ldfrag(&Bs[row * 64 + chunk * 8]);
            }
            #pragma unroll
            for (int m = 0; m < 4; ++m)
                #pragma unroll
                for (int n = 0; n < 4; ++n)
                    acc[m][n] = __builtin_amdgcn_mfma_f32_16x16x32_bf16(
                        aF[m], bF[n], acc[m][n], 0, 0, 0);
        }
    }

    int   rowTok[4][4];
    float rowP[4][4];
    bool  rowV[4][4];
    #pragma unroll
    for (int m = 0; m < 4; ++m)
        #pragma unroll
        for (int r = 0; r < 4; ++r) {
            int row = wm * 64 + m * 16 + (lane >> 4) * 4 + r;
            int gIdx = g0 + tm * 128 + row;
            if (gIdx < g1) {
                int entry = perm[gIdx];
                rowTok[m][r] = entry >> 1;
                rowP[m][r]   = prob[entry];
                rowV[m][r]   = true;
            } else rowV[m][r] = false;
        }
    #pragma unroll
    for (int n = 0; n < 4; ++n) {
        int col = tn * 128 + wn * 64 + n * 16 + (lane & 15);
        float bias = be[e * OUT_DIM + col];
        #pragma unroll
        for (int m = 0; m < 4; ++m)
            #pragma unroll
            for (int r = 0; r < 4; ++r)
                if (rowV[m][r]) {
                    float v = acc[m][n][r] + bias;
                    atomicAdd(&out[(size_t)rowTok[m][r] * OUT_DIM + col],
                              rowP[m][r] * v);
                }
    }
}

// ---- launch ----------------------------------------------------------------
extern "C" void kernel_launch(void* const* d_in, const int* in_sizes, int n_in,
                              void* d_out, int out_size, void* d_ws, size_t ws_size,
                              hipStream_t stream) {
    const float* x  = (const float*)d_in[0];
    const float* Wg = (const float*)d_in[1];
    const float* bg = (const float*)d_in[2];
    const float* We = (const float*)d_in[3];
    const float* be = (const float*)d_in[4];
    float* out = (float*)d_out;

    const size_t WEB_BYTES = (size_t)NUM_EXPERTS * OUT_DIM * IN_DIM * 2;  // 32 MB
    const size_t XB_BYTES  = (size_t)BTOK * IN_DIM * 2;                   // 16 MB
    const size_t MISC      = (size_t)NSLOT * 12 + 256 * NUM_EXPERTS * 8 + 4096;
    bool full = ws_size >= WEB_BYTES + XB_BYTES + MISC;

    char* w = (char*)d_ws;
    unsigned short* Web = nullptr;
    unsigned short* xb  = nullptr;
    if (full) {
        Web = (unsigned short*)w; w += WEB_BYTES;
        xb  = (unsigned short*)w; w += XB_BYTES;
    }
    int*   offsets     = (int*)w;    w += 128;
    int*   cursor      = (int*)w;    w += 64;
    int*   descs       = (int*)w;    w += (1 + MAX_DESC) * 4 + 60;
    int*   eidx        = (int*)w;    w += (size_t)NSLOT * 4;
    float* probArr     = (float*)w;  w += (size_t)NSLOT * 4;
    int*   perm        = (int*)w;    w += (size_t)NSLOT * 4;
    float* partialLoad = (float*)w;  w += 256 * NUM_EXPERTS * 4;
    int*   partialCnt  = (int*)w;    w += 256 * NUM_EXPERTS * 4;

    if (!full)
        hipMemsetAsync(d_out, 0, (size_t)out_size * sizeof(float), stream);

    gate_kernel<<<BTOK / 32, 256, 0, stream>>>(x, Wg, bg, eidx, probArr,
                                               partialLoad, partialCnt,
                                               full ? xb : nullptr, We,
                                               full ? Web : nullptr);
    finalize_gate<<<1, 256, 0, stream>>>(offsets, cursor, partialLoad, partialCnt,
                                         out + (size_t)BTOK * OUT_DIM, descs);
    scatter_kernel<<<BTOK / 256, 256, 0, stream>>>(eidx, cursor, perm);

    if (full) {
        expert_gemm_bf16<<<MAX_DESC * 8, 256, 0, stream>>>(
            xb, Web, perm, offsets, descs, (unsigned short*)d_out);
        combine_kernel<<<BTOK, 256, 0, stream>>>(out, eidx, probArr, be);
    } else {
        dim3 grid(OUT_DIM / 128, NSLOT / 128, NUM_EXPERTS);
        expert_gemm_f32<<<grid, 256, 0, stream>>>(x, We, be, perm, probArr,
                                                  offsets, out);
    }
}